// Round 13
// baseline (71.785 us; speedup 1.0000x reference)
//
#include <hip/hip_runtime.h>
#include <math.h>

#define GAMMA 9.6f
#define BETA  0.83f
#define LAMDA 10.0f
#define B_ 1024
#define D_ 512
#define C_ 10000
#define M0_ 20.0f     // fixed logit shift: max possible gamma*(fea+beta*c) ~ 17.8

// ---- ws layout (bytes) ----
#define WS_XB   0
#define WS_WB   1048576
#define WS_SU   11288576   // s_u  [1024] u32
#define WS_T    11292672   // T    [1024] f32
#define WS_SP   11296768   // sp   [1024] f32

typedef __attribute__((ext_vector_type(8))) short short8;
typedef __attribute__((ext_vector_type(4))) float floatx4;

__device__ __forceinline__ unsigned enc_f(float f) {
    unsigned i = __float_as_uint(f);
    return (i & 0x80000000u) ? ~i : (i | 0x80000000u);
}
__device__ __forceinline__ float dec_f(unsigned u) {
    return (u & 0x80000000u) ? __uint_as_float(u ^ 0x80000000u)
                             : __uint_as_float(~u);
}
__device__ __forceinline__ float softplus_f(float x) {
    return (x > 30.f) ? x : log1pf(expf(x));
}
__device__ __forceinline__ unsigned short f2bf_rne(float f) {
    unsigned u = __float_as_uint(f);
    u += 0x7FFFu + ((u >> 16) & 1u);
    return (unsigned short)(u >> 16);
}

// ---------------- normalize + convert to bf16 (+ fused init) ----------------
// wave-per-row: 256-thr block = 4 waves = 4 rows; lane holds 8 f32 (2 float4);
// pure shuffle reduce, no LDS, no __syncthreads. Nontemporal loads: the fp32
// sources are read exactly once (GEMM reads the bf16 copies) — don't cache.
__global__ __launch_bounds__(256) void normcvt_kernel(
    const float* __restrict__ input, const float* __restrict__ weight,
    unsigned short* __restrict__ xb, unsigned short* __restrict__ wb,
    unsigned* __restrict__ s_u, float* __restrict__ T) {
    const int lane = threadIdx.x & 63;
    const int row = blockIdx.x * 4 + (threadIdx.x >> 6);
    if (row < B_ && lane == 0) { s_u[row] = 0u; T[row] = 0.f; }

    const float* src = (row < B_) ? (input + (size_t)row * D_)
                                  : (weight + (size_t)(row - B_) * D_);
    floatx4 v0 = __builtin_nontemporal_load((const floatx4*)(src + lane * 8));
    floatx4 v1 = __builtin_nontemporal_load((const floatx4*)(src + lane * 8 + 4));
    float ss = v0[0] * v0[0] + v0[1] * v0[1] + v0[2] * v0[2] + v0[3] * v0[3]
             + v1[0] * v1[0] + v1[1] * v1[1] + v1[2] * v1[2] + v1[3] * v1[3];
    #pragma unroll
    for (int o = 32; o > 0; o >>= 1) ss += __shfl_xor(ss, o, 64);
    float inv = 1.0f / fmaxf(sqrtf(ss), 1e-12f);

    unsigned short* dst = (row < B_) ? (xb + (size_t)row * D_)
                                     : (wb + (size_t)(row - B_) * D_);
    ushort4 o4;
    o4.x = f2bf_rne(v0[0] * inv); o4.y = f2bf_rne(v0[1] * inv);
    o4.z = f2bf_rne(v0[2] * inv); o4.w = f2bf_rne(v0[3] * inv);
    *(ushort4*)(dst + lane * 8) = o4;
    o4.x = f2bf_rne(v1[0] * inv); o4.y = f2bf_rne(v1[1] * inv);
    o4.z = f2bf_rne(v1[2] * inv); o4.w = f2bf_rne(v1[3] * inv);
    *(ushort4*)(dst + lane * 8 + 4) = o4;
}

// ---------------- fused bf16 MFMA GEMM (128x128, 4 waves, 2-phase) ----------
// r7/r12's measured-best kernel. Only delta: fea stores are NONTEMPORAL —
// fea (41 MB) is written once and never re-read; streaming it through L2
// evicts the wb panels the XCD swizzle keeps hot (FETCH_SIZE 22 MB vs 11.5
// ideal). nt stores keep wb L2-resident.
// virtual A: rows 0..1023 = xb, rows 1024..2047 = wb[label[r]]
// B = wb, N = 10000, K = 512
// m-tiles 0..7: write fea + accumulate T_r / sp_r. tiles 8..15: row-max -> s_u
#define BM 128
#define BN 128
#define BK 32
#define NSTEP (D_ / BK)           // 16
#define NTILE_M 16
#define NTILE_N 79
#define NWG (NTILE_M * NTILE_N)   // 1264 = 8 * 158

__global__ __launch_bounds__(256) void mfma_gemm_kernel(
    const unsigned short* __restrict__ xb, const unsigned short* __restrict__ wb,
    const int* __restrict__ label, const float* __restrict__ cw,
    float* __restrict__ fea, unsigned* __restrict__ s_u,
    float* __restrict__ T, float* __restrict__ sp) {
    __shared__ __align__(16) unsigned short As[2][BM * BK];   // 2 x 8 KB
    __shared__ __align__(16) unsigned short Bs[2][BM * BK];   // 2 x 8 KB

    const int tid = threadIdx.x;
    // bijective XCD swizzle (1264 % 8 == 0), m-tile fastest within each chunk
    const int orig = (blockIdx.x & 7) * (NWG / 8) + (blockIdx.x >> 3);
    const int m0 = (orig & 15) * BM;
    const int n0 = (orig >> 4) * BN;
    const bool feaTile = (m0 < B_);

    const int arow = tid >> 2;          // 0..63
    const int kc8 = (tid & 3) * 8;      // bf16 element offset along K
    const unsigned short* asrc[2];
    const unsigned short* bsrc[2];
    #pragma unroll
    for (int q = 0; q < 2; q++) {
        int rm = m0 + arow + q * 64;
        const unsigned short* ab;
        if (rm < B_) ab = xb + (size_t)rm * D_;
        else         ab = wb + (size_t)label[rm - B_] * D_;
        asrc[q] = ab + kc8;
        int rn = n0 + arow + q * 64;
        if (rn >= C_) rn = C_ - 1;
        bsrc[q] = wb + (size_t)rn * D_ + kc8;
    }

    const int lane = tid & 63;
    const int wv = tid >> 6;            // wave 0..3 -> 2x2 of 64x64
    const int wr = (wv >> 1) * 64;
    const int wc = (wv & 1) * 64;
    const int l15 = lane & 15;
    const int hi = lane >> 4;           // 0..3

    floatx4 acc[4][4];
    #pragma unroll
    for (int i = 0; i < 4; i++)
        #pragma unroll
        for (int j = 0; j < 4; j++)
            acc[i][j] = (floatx4){0.f, 0.f, 0.f, 0.f};

#define STAGE(buf, kt)                                                         \
    {                                                                          \
        _Pragma("unroll")                                                      \
        for (int q = 0; q < 2; q++) {                                          \
            __builtin_amdgcn_global_load_lds(                                  \
                (const __attribute__((address_space(1))) void*)(asrc[q] + (kt)),\
                (__attribute__((address_space(3))) void*)((char*)&As[buf][0] + tid * 16 + q * 4096), \
                16, 0, 0);                                                     \
            __builtin_amdgcn_global_load_lds(                                  \
                (const __attribute__((address_space(1))) void*)(bsrc[q] + (kt)),\
                (__attribute__((address_space(3))) void*)((char*)&Bs[buf][0] + tid * 16 + q * 4096), \
                16, 0, 0);                                                     \
        }                                                                      \
    }

    // prologue: stage K-step 0 into buf 0
    STAGE(0, 0);
    __syncthreads();

    int cur = 0;
    for (int t = 0; t < NSTEP; ++t) {
        int ktn = (t + 1) * BK;
        if (ktn < D_) STAGE(cur ^ 1, ktn);   // prefetch next step (in flight)
        short8 a[4], b[4];
        #pragma unroll
        for (int i = 0; i < 4; i++)
            a[i] = *(const short8*)&As[cur][(wr + i * 16 + l15) * BK + hi * 8];
        #pragma unroll
        for (int j = 0; j < 4; j++)
            b[j] = *(const short8*)&Bs[cur][(wc + j * 16 + l15) * BK + hi * 8];
        #pragma unroll
        for (int i = 0; i < 4; i++)
            #pragma unroll
            for (int j = 0; j < 4; j++)
                acc[i][j] = __builtin_amdgcn_mfma_f32_16x16x32_bf16(
                    a[i], b[j], acc[i][j], 0, 0, 0);
        __syncthreads();   // drains vmcnt(0): prefetch landed; buf swap safe
        cur ^= 1;
    }

    if (feaTile) {
        int lbl_ir[4][4];
        #pragma unroll
        for (int i = 0; i < 4; i++)
            #pragma unroll
            for (int r = 0; r < 4; r++)
                lbl_ir[i][r] = label[m0 + wr + i * 16 + hi * 4 + r];
        float cwj[4];
        #pragma unroll
        for (int j = 0; j < 4; j++) {
            int n = n0 + wc + j * 16 + l15;
            cwj[j] = (n < C_) ? cw[n] : 0.f;
        }
        float rs[4][4];
        #pragma unroll
        for (int i = 0; i < 4; i++)
            #pragma unroll
            for (int r = 0; r < 4; r++) rs[i][r] = 0.f;

        #pragma unroll
        for (int i = 0; i < 4; i++) {
            #pragma unroll
            for (int j = 0; j < 4; j++) {
                int n = n0 + wc + j * 16 + l15;
                if (n < C_) {
                    int m = m0 + wr + i * 16 + hi * 4;
                    float* dst = fea + (size_t)m * C_ + n;
                    #pragma unroll
                    for (int r = 0; r < 4; r++) {
                        float v = acc[i][j][r];
                        __builtin_nontemporal_store(v, dst + (size_t)r * C_);
                        int l = lbl_ir[i][r];
                        if (n == l) sp[m + r] = v;
                        else rs[i][r] += expf(GAMMA * (v + BETA * cwj[j]) - M0_);
                    }
                }
            }
        }
        // 16-lane reduce + one atomicAdd per (i,r) row
        #pragma unroll
        for (int i = 0; i < 4; i++) {
            #pragma unroll
            for (int r = 0; r < 4; r++) {
                float s = rs[i][r];
                #pragma unroll
                for (int o = 8; o > 0; o >>= 1) s += __shfl_xor(s, o, 64);
                if (l15 == 0)
                    atomicAdd(T + (m0 + wr + i * 16 + hi * 4 + r), s);
            }
        }
    } else {
        #pragma unroll
        for (int i = 0; i < 4; i++) {
            #pragma unroll
            for (int r = 0; r < 4; r++) {
                int row = m0 - B_ + wr + i * 16 + hi * 4 + r;   // 0..1023
                int l = label[row];
                float vmax = -2.f;
                #pragma unroll
                for (int j = 0; j < 4; j++) {
                    int n = n0 + wc + j * 16 + l15;
                    float v = fminf(fmaxf(acc[i][j][r], -1.f), 1.f);
                    if (n == l) v = 0.f;               // diagonal zeroed
                    if (n < C_) vmax = fmaxf(vmax, v);
                }
                #pragma unroll
                for (int o = 8; o > 0; o >>= 1)
                    vmax = fmaxf(vmax, __shfl_xor(vmax, o, 64));
                if (l15 == 0) atomicMax(s_u + row, enc_f(vmax));
            }
        }
    }
}

// ---------------- final scalar ----------------
__global__ __launch_bounds__(1024) void final_kernel(
    const unsigned* __restrict__ s_u, const float* __restrict__ T,
    const float* __restrict__ sp, float* __restrict__ out_loss) {
    int tid = threadIdx.x;
    float lse = M0_ + logf(T[tid]) - GAMMA * sp[tid];
    float lr = softplus_f(lse);
    float sv = dec_f(s_u[tid]);
    #pragma unroll
    for (int o = 32; o > 0; o >>= 1) {
        lr += __shfl_xor(lr, o, 64);
        sv += __shfl_xor(sv, o, 64);
    }
    __shared__ float red_l[16], red_s[16];
    if ((tid & 63) == 0) { red_l[tid >> 6] = lr; red_s[tid >> 6] = sv; }
    __syncthreads();
    if (tid == 0) {
        float tl = 0.f, ts = 0.f;
        #pragma unroll
        for (int w = 0; w < 16; w++) { tl += red_l[w]; ts += red_s[w]; }
        float loss_w = softplus_f(ts / (float)B_ + 0.5f);
        *out_loss = tl / (float)B_ + LAMDA * loss_w;
    }
}

extern "C" void kernel_launch(void* const* d_in, const int* in_sizes, int n_in,
                              void* d_out, int out_size, void* d_ws, size_t ws_size,
                              hipStream_t stream) {
    const float* input  = (const float*)d_in[0];
    const float* weight = (const float*)d_in[1];
    const float* cw     = (const float*)d_in[2];
    const int*   label  = (const int*)d_in[3];
    float* out = (float*)d_out;

    char* ws = (char*)d_ws;
    unsigned short* xb = (unsigned short*)(ws + WS_XB);
    unsigned short* wb = (unsigned short*)(ws + WS_WB);
    unsigned* s_u      = (unsigned*)(ws + WS_SU);
    float*    T        = (float*)(ws + WS_T);
    float*    sp       = (float*)(ws + WS_SP);

    normcvt_kernel<<<(B_ + C_) / 4, 256, 0, stream>>>(input, weight, xb, wb, s_u, T);

    mfma_gemm_kernel<<<NWG, 256, 0, stream>>>(xb, wb, label, cw, out, s_u, T, sp);

    final_kernel<<<1, 1024, 0, stream>>>(s_u, T, sp, out + (size_t)B_ * C_);
}

// Round 14
// 69.672 us; speedup vs baseline: 1.0303x; 1.0303x over previous
//
#include <hip/hip_runtime.h>
#include <math.h>

#define GAMMA 9.6f
#define BETA  0.83f
#define LAMDA 10.0f
#define B_ 1024
#define D_ 512
#define C_ 10000
#define M0_ 20.0f     // fixed logit shift: max possible gamma*(fea+beta*c) ~ 17.8

// ---- ws layout (bytes) ----
#define WS_XB   0
#define WS_WB   1048576
#define WS_SU   11288576   // s_u  [1024] u32
#define WS_T    11292672   // T    [1024] f32
#define WS_SP   11296768   // sp   [1024] f32

typedef __attribute__((ext_vector_type(8))) short short8;
typedef __attribute__((ext_vector_type(4))) float floatx4;

__device__ __forceinline__ unsigned enc_f(float f) {
    unsigned i = __float_as_uint(f);
    return (i & 0x80000000u) ? ~i : (i | 0x80000000u);
}
__device__ __forceinline__ float dec_f(unsigned u) {
    return (u & 0x80000000u) ? __uint_as_float(u ^ 0x80000000u)
                             : __uint_as_float(~u);
}
__device__ __forceinline__ float softplus_f(float x) {
    return (x > 30.f) ? x : log1pf(expf(x));
}
__device__ __forceinline__ unsigned short f2bf_rne(float f) {
    unsigned u = __float_as_uint(f);
    u += 0x7FFFu + ((u >> 16) & 1u);
    return (unsigned short)(u >> 16);
}

// ---------------- normalize + convert to bf16 (+ fused init) ----------------
// wave-per-row: 256-thr block = 4 waves = 4 rows; lane holds 8 f32 (2 float4);
// pure shuffle reduce, no LDS, no __syncthreads. 2756 blocks.
__global__ __launch_bounds__(256) void normcvt_kernel(
    const float* __restrict__ input, const float* __restrict__ weight,
    unsigned short* __restrict__ xb, unsigned short* __restrict__ wb,
    unsigned* __restrict__ s_u, float* __restrict__ T) {
    const int lane = threadIdx.x & 63;
    const int row = blockIdx.x * 4 + (threadIdx.x >> 6);
    if (row < B_ && lane == 0) { s_u[row] = 0u; T[row] = 0.f; }

    const float* src = (row < B_) ? (input + (size_t)row * D_)
                                  : (weight + (size_t)(row - B_) * D_);
    float4 v0 = *(const float4*)(src + lane * 8);
    float4 v1 = *(const float4*)(src + lane * 8 + 4);
    float ss = v0.x * v0.x + v0.y * v0.y + v0.z * v0.z + v0.w * v0.w
             + v1.x * v1.x + v1.y * v1.y + v1.z * v1.z + v1.w * v1.w;
    #pragma unroll
    for (int o = 32; o > 0; o >>= 1) ss += __shfl_xor(ss, o, 64);
    float inv = 1.0f / fmaxf(sqrtf(ss), 1e-12f);

    unsigned short* dst = (row < B_) ? (xb + (size_t)row * D_)
                                     : (wb + (size_t)(row - B_) * D_);
    ushort4 o4;
    o4.x = f2bf_rne(v0.x * inv); o4.y = f2bf_rne(v0.y * inv);
    o4.z = f2bf_rne(v0.z * inv); o4.w = f2bf_rne(v0.w * inv);
    *(ushort4*)(dst + lane * 8) = o4;
    o4.x = f2bf_rne(v1.x * inv); o4.y = f2bf_rne(v1.y * inv);
    o4.z = f2bf_rne(v1.z * inv); o4.w = f2bf_rne(v1.w * inv);
    *(ushort4*)(dst + lane * 8 + 4) = o4;
}

// ---------------- fused bf16 MFMA GEMM (128x128, 4 waves, 2-phase) ----------
// Measured-best structure of the session (r7/r12, 70.05 us total).
// virtual A: rows 0..1023 = xb, rows 1024..2047 = wb[label[r]]
// B = wb, N = 10000, K = 512
// m-tiles 0..7: write fea + accumulate T_r / sp_r. tiles 8..15: row-max -> s_u
#define BM 128
#define BN 128
#define BK 32
#define NSTEP (D_ / BK)           // 16
#define NTILE_M 16
#define NTILE_N 79
#define NWG (NTILE_M * NTILE_N)   // 1264 = 8 * 158

__global__ __launch_bounds__(256) void mfma_gemm_kernel(
    const unsigned short* __restrict__ xb, const unsigned short* __restrict__ wb,
    const int* __restrict__ label, const float* __restrict__ cw,
    float* __restrict__ fea, unsigned* __restrict__ s_u,
    float* __restrict__ T, float* __restrict__ sp) {
    __shared__ __align__(16) unsigned short As[2][BM * BK];   // 2 x 8 KB
    __shared__ __align__(16) unsigned short Bs[2][BM * BK];   // 2 x 8 KB

    const int tid = threadIdx.x;
    // bijective XCD swizzle (1264 % 8 == 0), m-tile fastest within each chunk
    const int orig = (blockIdx.x & 7) * (NWG / 8) + (blockIdx.x >> 3);
    const int m0 = (orig & 15) * BM;
    const int n0 = (orig >> 4) * BN;
    const bool feaTile = (m0 < B_);

    const int arow = tid >> 2;          // 0..63
    const int kc8 = (tid & 3) * 8;      // bf16 element offset along K
    const unsigned short* asrc[2];
    const unsigned short* bsrc[2];
    #pragma unroll
    for (int q = 0; q < 2; q++) {
        int rm = m0 + arow + q * 64;
        const unsigned short* ab;
        if (rm < B_) ab = xb + (size_t)rm * D_;
        else         ab = wb + (size_t)label[rm - B_] * D_;
        asrc[q] = ab + kc8;
        int rn = n0 + arow + q * 64;
        if (rn >= C_) rn = C_ - 1;
        bsrc[q] = wb + (size_t)rn * D_ + kc8;
    }

    const int lane = tid & 63;
    const int wv = tid >> 6;            // wave 0..3 -> 2x2 of 64x64
    const int wr = (wv >> 1) * 64;
    const int wc = (wv & 1) * 64;
    const int l15 = lane & 15;
    const int hi = lane >> 4;           // 0..3

    floatx4 acc[4][4];
    #pragma unroll
    for (int i = 0; i < 4; i++)
        #pragma unroll
        for (int j = 0; j < 4; j++)
            acc[i][j] = (floatx4){0.f, 0.f, 0.f, 0.f};

#define STAGE(buf, kt)                                                         \
    {                                                                          \
        _Pragma("unroll")                                                      \
        for (int q = 0; q < 2; q++) {                                          \
            __builtin_amdgcn_global_load_lds(                                  \
                (const __attribute__((address_space(1))) void*)(asrc[q] + (kt)),\
                (__attribute__((address_space(3))) void*)((char*)&As[buf][0] + tid * 16 + q * 4096), \
                16, 0, 0);                                                     \
            __builtin_amdgcn_global_load_lds(                                  \
                (const __attribute__((address_space(1))) void*)(bsrc[q] + (kt)),\
                (__attribute__((address_space(3))) void*)((char*)&Bs[buf][0] + tid * 16 + q * 4096), \
                16, 0, 0);                                                     \
        }                                                                      \
    }

    // prologue: stage K-step 0 into buf 0
    STAGE(0, 0);
    __syncthreads();

    int cur = 0;
    for (int t = 0; t < NSTEP; ++t) {
        int ktn = (t + 1) * BK;
        if (ktn < D_) STAGE(cur ^ 1, ktn);   // prefetch next step (in flight)
        short8 a[4], b[4];
        #pragma unroll
        for (int i = 0; i < 4; i++)
            a[i] = *(const short8*)&As[cur][(wr + i * 16 + l15) * BK + hi * 8];
        #pragma unroll
        for (int j = 0; j < 4; j++)
            b[j] = *(const short8*)&Bs[cur][(wc + j * 16 + l15) * BK + hi * 8];
        #pragma unroll
        for (int i = 0; i < 4; i++)
            #pragma unroll
            for (int j = 0; j < 4; j++)
                acc[i][j] = __builtin_amdgcn_mfma_f32_16x16x32_bf16(
                    a[i], b[j], acc[i][j], 0, 0, 0);
        __syncthreads();   // drains vmcnt(0): prefetch landed; buf swap safe
        cur ^= 1;
    }

    if (feaTile) {
        int lbl_ir[4][4];
        #pragma unroll
        for (int i = 0; i < 4; i++)
            #pragma unroll
            for (int r = 0; r < 4; r++)
                lbl_ir[i][r] = label[m0 + wr + i * 16 + hi * 4 + r];
        float cwj[4];
        #pragma unroll
        for (int j = 0; j < 4; j++) {
            int n = n0 + wc + j * 16 + l15;
            cwj[j] = (n < C_) ? cw[n] : 0.f;
        }
        float rs[4][4];
        #pragma unroll
        for (int i = 0; i < 4; i++)
            #pragma unroll
            for (int r = 0; r < 4; r++) rs[i][r] = 0.f;

        #pragma unroll
        for (int i = 0; i < 4; i++) {
            #pragma unroll
            for (int j = 0; j < 4; j++) {
                int n = n0 + wc + j * 16 + l15;
                if (n < C_) {
                    int m = m0 + wr + i * 16 + hi * 4;
                    float* dst = fea + (size_t)m * C_ + n;
                    #pragma unroll
                    for (int r = 0; r < 4; r++) {
                        float v = acc[i][j][r];
                        dst[(size_t)r * C_] = v;
                        int l = lbl_ir[i][r];
                        if (n == l) sp[m + r] = v;
                        else rs[i][r] += expf(GAMMA * (v + BETA * cwj[j]) - M0_);
                    }
                }
            }
        }
        // 16-lane reduce + one atomicAdd per (i,r) row
        #pragma unroll
        for (int i = 0; i < 4; i++) {
            #pragma unroll
            for (int r = 0; r < 4; r++) {
                float s = rs[i][r];
                #pragma unroll
                for (int o = 8; o > 0; o >>= 1) s += __shfl_xor(s, o, 64);
                if (l15 == 0)
                    atomicAdd(T + (m0 + wr + i * 16 + hi * 4 + r), s);
            }
        }
    } else {
        #pragma unroll
        for (int i = 0; i < 4; i++) {
            #pragma unroll
            for (int r = 0; r < 4; r++) {
                int row = m0 - B_ + wr + i * 16 + hi * 4 + r;   // 0..1023
                int l = label[row];
                float vmax = -2.f;
                #pragma unroll
                for (int j = 0; j < 4; j++) {
                    int n = n0 + wc + j * 16 + l15;
                    float v = fminf(fmaxf(acc[i][j][r], -1.f), 1.f);
                    if (n == l) v = 0.f;               // diagonal zeroed
                    if (n < C_) vmax = fmaxf(vmax, v);
                }
                #pragma unroll
                for (int o = 8; o > 0; o >>= 1)
                    vmax = fmaxf(vmax, __shfl_xor(vmax, o, 64));
                if (l15 == 0) atomicMax(s_u + row, enc_f(vmax));
            }
        }
    }
}

// ---------------- final scalar ----------------
__global__ __launch_bounds__(1024) void final_kernel(
    const unsigned* __restrict__ s_u, const float* __restrict__ T,
    const float* __restrict__ sp, float* __restrict__ out_loss) {
    int tid = threadIdx.x;
    float lse = M0_ + logf(T[tid]) - GAMMA * sp[tid];
    float lr = softplus_f(lse);
    float sv = dec_f(s_u[tid]);
    #pragma unroll
    for (int o = 32; o > 0; o >>= 1) {
        lr += __shfl_xor(lr, o, 64);
        sv += __shfl_xor(sv, o, 64);
    }
    __shared__ float red_l[16], red_s[16];
    if ((tid & 63) == 0) { red_l[tid >> 6] = lr; red_s[tid >> 6] = sv; }
    __syncthreads();
    if (tid == 0) {
        float tl = 0.f, ts = 0.f;
        #pragma unroll
        for (int w = 0; w < 16; w++) { tl += red_l[w]; ts += red_s[w]; }
        float loss_w = softplus_f(ts / (float)B_ + 0.5f);
        *out_loss = tl / (float)B_ + LAMDA * loss_w;
    }
}

extern "C" void kernel_launch(void* const* d_in, const int* in_sizes, int n_in,
                              void* d_out, int out_size, void* d_ws, size_t ws_size,
                              hipStream_t stream) {
    const float* input  = (const float*)d_in[0];
    const float* weight = (const float*)d_in[1];
    const float* cw     = (const float*)d_in[2];
    const int*   label  = (const int*)d_in[3];
    float* out = (float*)d_out;

    char* ws = (char*)d_ws;
    unsigned short* xb = (unsigned short*)(ws + WS_XB);
    unsigned short* wb = (unsigned short*)(ws + WS_WB);
    unsigned* s_u      = (unsigned*)(ws + WS_SU);
    float*    T        = (float*)(ws + WS_T);
    float*    sp       = (float*)(ws + WS_SP);

    normcvt_kernel<<<(B_ + C_) / 4, 256, 0, stream>>>(input, weight, xb, wb, s_u, T);

    mfma_gemm_kernel<<<NWG, 256, 0, stream>>>(xb, wb, label, cw, out, s_u, T, sp);

    final_kernel<<<1, 1024, 0, stream>>>(s_u, T, sp, out + (size_t)B_ * C_);
}